// Round 3
// baseline (403.858 us; speedup 1.0000x reference)
//
#include <hip/hip_runtime.h>
#include <math.h>

#define B_  8
#define T_  8192
#define T2_ 4096
#define F_  512
#define F2_ 256
#define K_  8
#define S_  64          // slots per column; cand = B*F*S*K*8B = 17 MB
#define L_  (T2_ / S_)  // 64 t2 per slot

typedef unsigned long long u64;
typedef float fvec2 __attribute__((ext_vector_type(2)));

// Sorted-descending top-8 insert of packed key:
//   (abs_bits << 32) | ((T2-1-t2) << 1) | signbit
// Keys unique (t2 unique per column). On equal abs, larger (T2-1-t2) wins,
// i.e. lower index first — matching jax.lax.top_k. Sign rides in bit 0
// (below the index bits) so it never perturbs the ordering.
__device__ __forceinline__ void ins8(u64 (&a)[K_], u64 k) {
    if (k <= a[K_ - 1]) return;
#pragma unroll
    for (int j = 0; j < K_; ++j) {
        u64 hi = (k > a[j]) ? k : a[j];
        u64 lo = (k > a[j]) ? a[j] : k;
        a[j] = hi;
        k = lo;
    }
}

// Phase 1: one 256-thread block owns one (b, slot) pair and walks L_
// consecutive t2. 256 threads x 8B = one full 2KB row, so each iteration
// the block reads a CONTIGUOUS 4KB (even+odd row) and writes a CONTIGUOUS
// 4KB of main — 512 long perfectly-sequential streams machine-wide instead
// of ~4096 fragmented 4KB-strided ones (DRAM row-buffer locality; the
// 6.5 TB/s fill kernel walks memory this way). Detail zeroing is a separate
// dedicated memset (measured cheaper than fusing: 21us vs +29us marginal).
__global__ __launch_bounds__(256) void haar_phase1(
    const fvec2* __restrict__ x2, fvec2* __restrict__ mainOut,
    u64* __restrict__ cand)
{
    const int tx   = threadIdx.x;   // 0..255 = f2 (floats f = 2tx, 2tx+1)
    const int slot = blockIdx.x;    // 0..S_-1
    const int b    = blockIdx.y;
    const int t2_0 = slot * L_;

    u64 a0[K_], a1[K_];
#pragma unroll
    for (int j = 0; j < K_; ++j) { a0[j] = 0; a1[j] = 0; }

    size_t re = ((size_t)b * T_ + 2 * (size_t)t2_0) * F2_ + tx;

#pragma unroll 2
    for (int t = 0; t < L_; ++t) {
        const fvec2 e = x2[re];
        const fvec2 o = x2[re + F2_];
        const fvec2 low = (e + o) * 0.5f;
        mainOut[re]       = low;
        mainOut[re + F2_] = low;
        const unsigned dx = __float_as_uint(e.x - o.x);
        const unsigned dy = __float_as_uint(e.y - o.y);
        const unsigned loBase = (unsigned)(T2_ - 1 - (t2_0 + t)) << 1;
        ins8(a0, ((u64)(dx & 0x7fffffffu) << 32) | (loBase | (dx >> 31)));
        ins8(a1, ((u64)(dy & 0x7fffffffu) << 32) | (loBase | (dy >> 31)));
        re += 2 * F2_;
    }

    // cand layout: (col * S_ + slot) * 8 + j, col = b*F + f. 64B line/list.
    const size_t colBase = (size_t)b * F_ + 2 * (size_t)tx;
    u64* d0 = cand + ((colBase + 0) * S_ + slot) * K_;
    u64* d1 = cand + ((colBase + 1) * S_ + slot) * K_;
#pragma unroll
    for (int j = 0; j < K_; ++j) { d0[j] = a0[j]; d1[j] = a1[j]; }
}

// Phase 2: one wave per column. Coalesced candidate reads (S_*K_ = 512 =
// exactly 8 per lane), per-lane top-8, 8 rounds of wave-wide u64 argmax,
// then lanes 0..7 scatter the winners. The detail VALUE is reconstructed
// from the key (abs bits + sign bit) — no re-read of x at all.
__global__ __launch_bounds__(256) void haar_phase2(
    const u64* __restrict__ cand, float* __restrict__ det)
{
    const int lane = threadIdx.x & 63;
    const int wv   = threadIdx.x >> 6;
    const int col  = blockIdx.x * 4 + wv;      // b*F + f
    const int b    = col >> 9;
    const int f    = col & (F_ - 1);

    const u64* c = cand + (size_t)col * (S_ * K_);
    u64 a[K_];
#pragma unroll
    for (int j = 0; j < K_; ++j) a[j] = 0;
#pragma unroll
    for (int e = 0; e < K_; ++e) ins8(a, c[lane + 64 * e]);

    u64 wkey = 0;
#pragma unroll
    for (int j = 0; j < K_; ++j) {
        u64 m = a[0];
#pragma unroll
        for (int s = 32; s > 0; s >>= 1) {
            u64 t = __shfl_xor(m, s, 64);
            m = (t > m) ? t : m;
        }
        if (a[0] == m) {            // exactly one lane (keys unique)
#pragma unroll
            for (int q = 0; q < K_ - 1; ++q) a[q] = a[q + 1];
            a[K_ - 1] = 0;
        }
        if (lane == j) wkey = m;
    }

    if (lane < K_) {
        const unsigned lo = (unsigned)wkey;
        const int t2 = T2_ - 1 - (int)(lo >> 1);
        float v = __uint_as_float((unsigned)(wkey >> 32)) * 0.5f;
        if (lo & 1u) v = -v;
        const size_t re = ((size_t)b * T_ + 2 * (size_t)t2) * F_ + f;
        det[re]      = v;
        det[re + F_] = -v;
    }
}

extern "C" void kernel_launch(void* const* d_in, const int* in_sizes, int n_in,
                              void* d_out, int out_size, void* d_ws, size_t ws_size,
                              hipStream_t stream) {
    const float* x = (const float*)d_in[0];
    float* out = (float*)d_out;
    float* detail = out + (size_t)B_ * T_ * F_;

    // Zero the detail half at dedicated-fill bandwidth (~21us); phase2
    // scatters the 8 nonzero rows per column afterwards (stream order).
    hipMemsetAsync(detail, 0, (size_t)B_ * T_ * F_ * sizeof(float), stream);

    // Workspace: B*F*S*K u64 keys = 17 MB (harness provides 1 GB).
    u64* cand = (u64*)d_ws;

    hipLaunchKernelGGL(haar_phase1, dim3(S_, B_), dim3(256), 0, stream,
                       (const fvec2*)x, (fvec2*)out, cand);

    const int nb = (B_ * F_) / 4;   // one wave per column, 4 waves/block
    hipLaunchKernelGGL(haar_phase2, dim3(nb), dim3(256), 0, stream,
                       cand, detail);
}